// Round 8
// baseline (99.805 us; speedup 1.0000x reference)
//
#include <hip/hip_runtime.h>
#include <math.h>

typedef _Float16 v8h __attribute__((ext_vector_type(8)));
typedef float    v4f __attribute__((ext_vector_type(4)));

#define NB    16       // batch elements per block (one 16-row MFMA tile)
#define DSTR  264      // zh row stride in halves
#define WSTR  68       // wbuf/gbuf per-batch stride (floats)
#define EPSLN 1e-5f

struct KP {
  const float* Z[8];
  const float* A;
  const float *W0, *b0, *g0, *be0, *Wg0, *bg0;
  const float *b1, *g1, *be1, *bg1;
  const float *b2, *g2, *be2, *bg2;
  const float *bout;
  const _Float16 *WgT1, *WgT2, *WT1, *WT2, *WoT;
  float* out;
};

// ---- combined weight conversion: dst[i][o][f] = (o<Osrc) ? src[i][f][o] : 0 (f16)
__device__ __forceinline__ void cvt_one(const float* __restrict__ src, _Float16* __restrict__ dst,
                                        int F, int Osrc, int Opad, int t) {
  const int f  = t % F;
  const int io = t / F;
  const int o  = io % Opad;
  const int i  = io / Opad;
  dst[t] = (o < Osrc) ? (_Float16)src[(i * F + f) * Osrc + o] : (_Float16)0.f;
}

#define E1 114688   // Wg1 -> WgT1 (F=1792, 7->8)
#define E2 57344    // Wg2 -> WgT2 (F=896, 7->8)
#define E3 4096     // Wout -> WoT (F=64, 5->8)
#define E4 262144   // W1 -> WT1 (F=256, 128)
#define E5 65536    // W2 -> WT2 (F=128, 64)

__global__ void cvt_all(const float* __restrict__ Wg1, const float* __restrict__ Wg2,
                        const float* __restrict__ Wout, const float* __restrict__ W1,
                        const float* __restrict__ W2, _Float16* __restrict__ ws) {
  int t = blockIdx.x * 256 + threadIdx.x;
  if (t < E1) { cvt_one(Wg1, ws, 1792, 7, 8, t); return; }
  t -= E1;
  if (t < E2) { cvt_one(Wg2, ws + E1, 896, 7, 8, t); return; }
  t -= E2;
  if (t < E3) { cvt_one(Wout, ws + E1 + E2, 64, 5, 8, t); return; }
  t -= E3;
  if (t < E4) { cvt_one(W1, ws + E1 + E2 + E3, 256, 128, 128, t); return; }
  t -= E4;
  if (t < E5) { cvt_one(W2, ws + E1 + E2 + E3 + E4, 128, 64, 64, t); return; }
}

// One MFMA layer, M=16. Gate uses 4 independent MFMA chains; B-frags software-
// pipelined. wbuf columns for node i are produced and consumed by wave i only,
// and zh is read-only between the entry and the pre-write barrier -> the only
// barriers needed are the two around the zh write-back.
template<int D, int O>
__device__ __forceinline__ void mfma_layer(
    _Float16* __restrict__ zh, float* __restrict__ wbuf, const float* __restrict__ gbuf,
    const _Float16* __restrict__ WgT, const float* __restrict__ bg,
    const _Float16* __restrict__ WT, const float* __restrict__ bias,
    const float* __restrict__ g, const float* __restrict__ be,
    int i, int q, int r)
{
  constexpr int KS = D / 32;
  constexpr int NT = O / 16;

  const _Float16* WgB = WgT + (size_t)(i * 8 + r) * (7 * D) + q * 8;  // gate B rows
  const _Float16* WB  = WT  + (size_t)(i * O + r) * D + q * 8;        // dense B rows

  // ---------------- gate: logits[16b x 16(7)], 4 independent chains ----------------
  v4f ca0 = (v4f){0.f,0.f,0.f,0.f}, ca1 = ca0, ca2 = ca0, ca3 = ca0;
  {
    v8h gbf[7];
    #pragma unroll
    for (int nb = 0; nb < 7; ++nb) gbf[nb] = *(const v8h*)(WgB + nb * D);
    #pragma unroll
    for (int ks = 0; ks < KS; ++ks) {
      const int d0 = ks * 32 + q * 8;
      v8h gbn[7];
      if (ks + 1 < KS) {
        #pragma unroll
        for (int nb = 0; nb < 7; ++nb)
          gbn[nb] = *(const v8h*)(WgB + nb * D + (ks + 1) * 32);   // prefetch next ks
      }
      #pragma unroll
      for (int nb = 0; nb < 7; ++nb) {
        const int nk = nb + (nb >= i);
        const v8h af = *(const v8h*)(zh + (nk * NB + r) * DSTR + d0);
        switch (nb & 3) {
          case 0: ca0 = __builtin_amdgcn_mfma_f32_16x16x32_f16(af, gbf[nb], ca0, 0, 0, 0); break;
          case 1: ca1 = __builtin_amdgcn_mfma_f32_16x16x32_f16(af, gbf[nb], ca1, 0, 0, 0); break;
          case 2: ca2 = __builtin_amdgcn_mfma_f32_16x16x32_f16(af, gbf[nb], ca2, 0, 0, 0); break;
          default: ca3 = __builtin_amdgcn_mfma_f32_16x16x32_f16(af, gbf[nb], ca3, 0, 0, 0); break;
        }
      }
      if (ks + 1 < KS) {
        #pragma unroll
        for (int nb = 0; nb < 7; ++nb) gbf[nb] = gbn[nb];
      }
    }
  }
  const v4f gacc = (ca0 + ca1) + (ca2 + ca3);

  // softmax over cols r<7 (16-lane groups), times input gates -> wbuf (wave-private cols)
  const float bgv = (r < 7) ? bg[i * 7 + r] : 0.f;
  #pragma unroll
  for (int reg = 0; reg < 4; ++reg) {
    const float v = gacc[reg] + bgv;
    float m = (r < 7) ? v : -3.0e38f;
    #pragma unroll
    for (int mk = 1; mk < 16; mk <<= 1) m = fmaxf(m, __shfl_xor(m, mk, 16));
    const float e = (r < 7) ? __expf(v - m) : 0.f;
    float s = e;
    #pragma unroll
    for (int mk = 1; mk < 16; mk <<= 1) s += __shfl_xor(s, mk, 16);
    const int b = q * 4 + reg;
    if (r < 7) wbuf[b * WSTR + i * 8 + r] = (e / s) * gbuf[b * WSTR + i * 8 + r];
  }
  // no barrier: wbuf cols of node i are same-wave; zh untouched since entry

  // ---------------- dense: h = (z_i + sum_k w_k z_nk) @ W_i + b ----------------
  v4f acc[NT];
  #pragma unroll
  for (int n = 0; n < NT; ++n) acc[n] = (v4f){0.f,0.f,0.f,0.f};

  _Float16 wh[7];
  #pragma unroll
  for (int nb = 0; nb < 7; ++nb)
    wh[nb] = (_Float16)wbuf[r * WSTR + i * 8 + nb];

  v8h dbf[NT];
  #pragma unroll
  for (int n = 0; n < NT; ++n) dbf[n] = *(const v8h*)(WB + (size_t)n * 16 * D);

  #pragma unroll
  for (int ks = 0; ks < KS; ++ks) {
    const int d0 = ks * 32 + q * 8;
    v8h dbn[NT];
    if (ks + 1 < KS) {
      #pragma unroll
      for (int n = 0; n < NT; ++n)
        dbn[n] = *(const v8h*)(WB + (size_t)n * 16 * D + (ks + 1) * 32);  // prefetch
    }
    v8h zn[7];
    #pragma unroll
    for (int nb = 0; nb < 7; ++nb) {
      const int nk = nb + (nb >= i);
      zn[nb] = *(const v8h*)(zh + ((nk * NB + r) * DSTR + d0));
    }
    v8h x = *(const v8h*)(zh + ((i * NB + r) * DSTR + d0));
    x = (x + (zn[0] * wh[0] + zn[1] * wh[1]))
      + ((zn[2] * wh[2] + zn[3] * wh[3])
      + ((zn[4] * wh[4] + zn[5] * wh[5]) + zn[6] * wh[6]));
    #pragma unroll
    for (int n = 0; n < NT; ++n)
      acc[n] = __builtin_amdgcn_mfma_f32_16x16x32_f16(x, dbf[n], acc[n], 0, 0, 0);
    if (ks + 1 < KS) {
      #pragma unroll
      for (int n = 0; n < NT; ++n) dbf[n] = dbn[n];
    }
  }

  // bias + LayerNorm + relu in regs (C/D: col=n*16+r, row=q*4+reg)
  float bv[NT], gv[NT], bev[NT];
  #pragma unroll
  for (int n = 0; n < NT; ++n) {
    const int o = n * 16 + r;
    bv[n] = bias[i * O + o]; gv[n] = g[i * O + o]; bev[n] = be[i * O + o];
  }
  #pragma unroll
  for (int reg = 0; reg < 4; ++reg) {
    float s1 = 0.f, s2 = 0.f;
    #pragma unroll
    for (int n = 0; n < NT; ++n) {
      const float h = acc[n][reg] + bv[n];
      acc[n][reg] = h;
      s1 += h; s2 += h * h;
    }
    #pragma unroll
    for (int mk = 1; mk < 16; mk <<= 1) { s1 += __shfl_xor(s1, mk, 16); s2 += __shfl_xor(s2, mk, 16); }
    const float mean = s1 * (1.f / O);
    const float var  = s2 * (1.f / O) - mean * mean;
    const float rs   = rsqrtf(var + EPSLN);
    #pragma unroll
    for (int n = 0; n < NT; ++n) {
      const float h = (acc[n][reg] - mean) * rs * gv[n] + bev[n];
      acc[n][reg] = fmaxf(h, 0.f);
    }
  }
  __syncthreads();   // all waves done reading zh before overwrite
  #pragma unroll
  for (int n = 0; n < NT; ++n)
    #pragma unroll
    for (int reg = 0; reg < 4; ++reg) {
      const int b = q * 4 + reg;
      zh[(i * NB + b) * DSTR + n * 16 + r] = (_Float16)acc[n][reg];
    }
  __syncthreads();
}

__launch_bounds__(512, 4)
__global__ void actor_mfma(KP p)
{
  __shared__ __align__(16) _Float16 zh[8 * NB * DSTR];   // [node][b][d]  67.6 KB
  __shared__ float wbuf[NB * WSTR];                      // 4.4 KB
  __shared__ float gbuf[NB * WSTR];                      // 4.4 KB
  __shared__ float xbuf[8 * NB * 4];                     // 2.0 KB

  const int i = threadIdx.x >> 6;        // wave = node
  const int u = threadIdx.x & 63;
  const int q = u >> 4, r = u & 15;
  const int bbase = blockIdx.x * NB;

  // ---- init: Z (f16) + gates
  {
    if (u < NB * 3) {
      const int b = u / 3, d = u - 3 * (u / 3);
      zh[(i * NB + b) * DSTR + d] = (_Float16)p.Z[i][(size_t)(bbase + b) * 3 + d];
    }
    for (int t = threadIdx.x; t < NB * 64; t += 512) {
      const int b = t >> 6, ik = t & 63;
      const int ii = ik >> 3, k = ik & 7;
      if (k < 7) {
        const int j = k + (k >= ii);
        const int gidx = (ii == 0 && j <= 3) ? j : 8 * j + ii;
        gbuf[b * WSTR + ik] = p.A[(size_t)(bbase + b) * 64 + gidx];
      }
    }
  }
  __syncthreads();

  // ================= layer 0 (VALU, tiny K) =================
  for (int c = 0; c < NB / 8; ++c) {
    const int b = c * 8 + (u >> 3), o8 = u & 7;
    float v = -3.0e38f;
    if (o8 < 7) {
      v = p.bg0[i * 7 + o8];
      #pragma unroll
      for (int k = 0; k < 7; ++k) {
        const int nk = k + (k >= i);
        const _Float16* zp = zh + (nk * NB + b) * DSTR;
        const float* wp = p.Wg0 + (i * 21 + k * 3) * 7 + o8;
        v += (float)zp[0] * wp[0] + (float)zp[1] * wp[7] + (float)zp[2] * wp[14];
      }
    }
    float m = v;
    #pragma unroll
    for (int mk = 1; mk < 8; mk <<= 1) m = fmaxf(m, __shfl_xor(m, mk, 8));
    const float e = (o8 < 7) ? __expf(v - m) : 0.f;
    float s = e;
    #pragma unroll
    for (int mk = 1; mk < 8; mk <<= 1) s += __shfl_xor(s, mk, 8);
    if (o8 < 7) wbuf[b * WSTR + i * 8 + o8] = (e / s) * gbuf[b * WSTR + i * 8 + o8];
  }
  // wbuf cols wave-private -> no barrier
  // NZ0 -> xbuf (wave-private rows; reads zh of neighbors)
  if (u < NB * 3) {
    const int b = u / 3, d = u - 3 * (u / 3);
    float x = (float)zh[(i * NB + b) * DSTR + d];
    #pragma unroll
    for (int k = 0; k < 7; ++k) {
      const int nk = k + (k >= i);
      x += wbuf[b * WSTR + i * 8 + k] * (float)zh[(nk * NB + b) * DSTR + d];
    }
    xbuf[(i * NB + b) * 4 + d] = x;
  }
  // REQUIRED barrier: dense0 below OVERWRITES zh[i][b][*] while other waves'
  // NZ0/gate0 may still be reading zh[nk=i][b][d<3] (cross-wave WAR). R7's
  // removal of this barrier was the correctness bug.
  __syncthreads();
  // dense0: O=256, K=3 ; writes zh[i][b][0..255]
  {
    const int bh = u >> 5, lo = u & 31, o = lo * 8;
    float w0r[3][8], b0r[8], g0r[8], be0r[8];
    #pragma unroll
    for (int d = 0; d < 3; ++d)
      #pragma unroll
      for (int j = 0; j < 8; ++j) w0r[d][j] = p.W0[(i * 3 + d) * 256 + o + j];
    #pragma unroll
    for (int j = 0; j < 8; ++j) {
      b0r[j] = p.b0[i * 256 + o + j];
      g0r[j] = p.g0[i * 256 + o + j];
      be0r[j] = p.be0[i * 256 + o + j];
    }
    for (int it = 0; it < NB / 2; ++it) {
      const int b = it * 2 + bh;
      const float x0 = xbuf[(i * NB + b) * 4 + 0];
      const float x1 = xbuf[(i * NB + b) * 4 + 1];
      const float x2 = xbuf[(i * NB + b) * 4 + 2];
      float h[8], s1 = 0.f, s2 = 0.f;
      #pragma unroll
      for (int j = 0; j < 8; ++j) {
        const float v = b0r[j] + x0 * w0r[0][j] + x1 * w0r[1][j] + x2 * w0r[2][j];
        h[j] = v; s1 += v; s2 += v * v;
      }
      #pragma unroll
      for (int mk = 1; mk < 32; mk <<= 1) { s1 += __shfl_xor(s1, mk, 32); s2 += __shfl_xor(s2, mk, 32); }
      const float mean = s1 * (1.f / 256.f);
      const float var  = s2 * (1.f / 256.f) - mean * mean;
      const float rs   = rsqrtf(var + EPSLN);
      v8h hv;
      #pragma unroll
      for (int j = 0; j < 8; ++j)
        hv[j] = (_Float16)fmaxf((h[j] - mean) * rs * g0r[j] + be0r[j], 0.f);
      *(v8h*)(zh + (i * NB + b) * DSTR + o) = hv;
    }
  }
  __syncthreads();

  // ================= layers 1,2 (MFMA) =================
  mfma_layer<256, 128>(zh, wbuf, gbuf, p.WgT1, p.bg1, p.WT1, p.b1, p.g1, p.be1, i, q, r);
  mfma_layer<128, 64 >(zh, wbuf, gbuf, p.WgT2, p.bg2, p.WT2, p.b2, p.g2, p.be2, i, q, r);

  // ================= output 64 -> 5, tanh (VALU) =================
  {
    const int b8 = u >> 3, o8 = u & 7;
    v8h wreg[8];
    #pragma unroll
    for (int t8 = 0; t8 < 8; ++t8)
      wreg[t8] = *(const v8h*)(p.WoT + (i * 8 + o8) * 64 + t8 * 8);
    const float bo = (o8 < 5) ? p.bout[i * 5 + o8] : 0.f;
    for (int c = 0; c < NB / 8; ++c) {
      const int b = c * 8 + b8;
      const _Float16* zp = zh + (i * NB + b) * DSTR;
      float acc = bo;
      #pragma unroll
      for (int t8 = 0; t8 < 8; ++t8) {
        const v8h z8 = *(const v8h*)(zp + t8 * 8);
        #pragma unroll
        for (int j = 0; j < 8; ++j) acc += (float)z8[j] * (float)wreg[t8][j];
      }
      if (o8 < 5)
        p.out[((size_t)(bbase + b) * 8 + i) * 5 + o8] = tanhf(acc);
    }
  }
}

extern "C" void kernel_launch(void* const* d_in, const int* in_sizes, int n_in,
                              void* d_out, int out_size, void* d_ws, size_t ws_size,
                              hipStream_t stream) {
  KP p;
  for (int i = 0; i < 8; ++i) p.Z[i] = (const float*)d_in[1 + i];
  p.A   = (const float*)d_in[9];
  p.W0  = (const float*)d_in[10]; p.b0 = (const float*)d_in[11];
  p.g0  = (const float*)d_in[12]; p.be0 = (const float*)d_in[13];
  p.Wg0 = (const float*)d_in[14]; p.bg0 = (const float*)d_in[15];
  const float* W1  = (const float*)d_in[16]; p.b1 = (const float*)d_in[17];
  p.g1  = (const float*)d_in[18]; p.be1 = (const float*)d_in[19];
  const float* Wg1 = (const float*)d_in[20]; p.bg1 = (const float*)d_in[21];
  const float* W2  = (const float*)d_in[22]; p.b2 = (const float*)d_in[23];
  p.g2  = (const float*)d_in[24]; p.be2 = (const float*)d_in[25];
  const float* Wg2 = (const float*)d_in[26]; p.bg2 = (const float*)d_in[27];
  const float* Wout = (const float*)d_in[28]; p.bout = (const float*)d_in[29];
  p.out = (float*)d_out;

  _Float16* wsH = (_Float16*)d_ws;
  p.WgT1 = wsH;
  p.WgT2 = wsH + E1;
  p.WoT  = wsH + E1 + E2;
  p.WT1  = wsH + E1 + E2 + E3;
  p.WT2  = wsH + E1 + E2 + E3 + E4;

  const int total = E1 + E2 + E3 + E4 + E5;  // 503808
  hipLaunchKernelGGL(cvt_all, dim3((total + 255) / 256), dim3(256), 0, stream,
                     Wg1, Wg2, Wout, W1, W2, wsH);

  hipLaunchKernelGGL(actor_mfma, dim3(8192 / NB), dim3(512), 0, stream, p);
}

// Round 9
// 75.700 us; speedup vs baseline: 1.3184x; 1.3184x over previous
//
#include <hip/hip_runtime.h>
#include <math.h>

typedef _Float16 v8h __attribute__((ext_vector_type(8)));
typedef float    v4f __attribute__((ext_vector_type(4)));

#define NB    32       // batch elements per block (two 16-row MFMA tiles per wave)
#define DSTR  264      // zh row stride in halves
#define WSTR  68       // wbuf/gbuf per-batch stride (floats)
#define EPSLN 1e-5f

struct KP {
  const float* Z[8];
  const float* A;
  const float *W0, *b0, *g0, *be0, *Wg0, *bg0;
  const float *b1, *g1, *be1, *bg1;
  const float *b2, *g2, *be2, *bg2;
  const float *bout;
  const _Float16 *WgT1, *WgT2, *WT1, *WT2, *WoT;
  float* out;
};

// ---- combined weight conversion: dst[i][o][f] = (o<Osrc) ? src[i][f][o] : 0 (f16)
__device__ __forceinline__ void cvt_one(const float* __restrict__ src, _Float16* __restrict__ dst,
                                        int F, int Osrc, int Opad, int t) {
  const int f  = t % F;
  const int io = t / F;
  const int o  = io % Opad;
  const int i  = io / Opad;
  dst[t] = (o < Osrc) ? (_Float16)src[(i * F + f) * Osrc + o] : (_Float16)0.f;
}

#define E1 114688   // Wg1 -> WgT1 (F=1792, 7->8)
#define E2 57344    // Wg2 -> WgT2 (F=896, 7->8)
#define E3 4096     // Wout -> WoT (F=64, 5->8)
#define E4 262144   // W1 -> WT1 (F=256, 128)
#define E5 65536    // W2 -> WT2 (F=128, 64)

__global__ void cvt_all(const float* __restrict__ Wg1, const float* __restrict__ Wg2,
                        const float* __restrict__ Wout, const float* __restrict__ W1,
                        const float* __restrict__ W2, _Float16* __restrict__ ws) {
  int t = blockIdx.x * 256 + threadIdx.x;
  if (t < E1) { cvt_one(Wg1, ws, 1792, 7, 8, t); return; }
  t -= E1;
  if (t < E2) { cvt_one(Wg2, ws + E1, 896, 7, 8, t); return; }
  t -= E2;
  if (t < E3) { cvt_one(Wout, ws + E1 + E2, 64, 5, 8, t); return; }
  t -= E3;
  if (t < E4) { cvt_one(W1, ws + E1 + E2 + E3, 256, 128, 128, t); return; }
  t -= E4;
  if (t < E5) { cvt_one(W2, ws + E1 + E2 + E3 + E4, 128, 64, 64, t); return; }
}

// One MFMA layer, M=2x16. Gate B-frags come PRELOADED (gpre, issued by the
// previous phase); dense ks=0 B-frags hoisted above the gate phase; NPRE
// next-phase B-frags issued after the dense k-loop so they fly during
// LN + barriers. wbuf cols of node i are same-wave -> no barrier after softmax.
template<int D, int O, int NPRE>
__device__ __forceinline__ void mfma_layer(
    _Float16* __restrict__ zh, float* __restrict__ wbuf, const float* __restrict__ gbuf,
    const v8h* gpre,
    const _Float16* __restrict__ WgT, const float* __restrict__ bg,
    const _Float16* __restrict__ WT, const float* __restrict__ bias,
    const float* __restrict__ g, const float* __restrict__ be,
    const _Float16* __restrict__ preBase, int preStride, v8h* pre,
    int i, int q, int r)
{
  constexpr int KS = D / 32;
  constexpr int NT = O / 16;

  const _Float16* WgB = WgT + (size_t)(i * 8 + r) * (7 * D) + q * 8;  // gate B rows
  const _Float16* WB  = WT  + (size_t)(i * O + r) * D + q * 8;        // dense B rows

  // hoisted dense ks=0 B-frags: the whole gate phase covers their latency
  v8h dbf[NT];
  #pragma unroll
  for (int n = 0; n < NT; ++n) dbf[n] = *(const v8h*)(WB + (size_t)n * 16 * D);

  v8h gbf[7];
  #pragma unroll
  for (int nb = 0; nb < 7; ++nb) gbf[nb] = gpre[nb];

  // ---------------- gate: logits[32b x 16(7)], 4 independent chains ----------------
  v4f ca[2][2];
  #pragma unroll
  for (int mt = 0; mt < 2; ++mt)
    #pragma unroll
    for (int c = 0; c < 2; ++c) ca[mt][c] = (v4f){0.f,0.f,0.f,0.f};

  #pragma unroll
  for (int ks = 0; ks < KS; ++ks) {
    const int d0 = ks * 32 + q * 8;
    v8h gbn[7];
    if (ks + 1 < KS) {
      #pragma unroll
      for (int nb = 0; nb < 7; ++nb)
        gbn[nb] = *(const v8h*)(WgB + nb * D + (ks + 1) * 32);   // prefetch next ks
    }
    #pragma unroll
    for (int nb = 0; nb < 7; ++nb) {
      const int nk = nb + (nb >= i);
      const v8h af0 = *(const v8h*)(zh + (nk * NB + r) * DSTR + d0);
      const v8h af1 = *(const v8h*)(zh + (nk * NB + 16 + r) * DSTR + d0);
      ca[0][nb & 1] = __builtin_amdgcn_mfma_f32_16x16x32_f16(af0, gbf[nb], ca[0][nb & 1], 0, 0, 0);
      ca[1][nb & 1] = __builtin_amdgcn_mfma_f32_16x16x32_f16(af1, gbf[nb], ca[1][nb & 1], 0, 0, 0);
    }
    if (ks + 1 < KS) {
      #pragma unroll
      for (int nb = 0; nb < 7; ++nb) gbf[nb] = gbn[nb];
    }
  }
  const v4f gacc[2] = { ca[0][0] + ca[0][1], ca[1][0] + ca[1][1] };

  // softmax over cols r<7 (16-lane groups), times input gates -> wbuf (same-wave cols)
  const float bgv = (r < 7) ? bg[i * 7 + r] : 0.f;
  #pragma unroll
  for (int mt = 0; mt < 2; ++mt) {
    #pragma unroll
    for (int reg = 0; reg < 4; ++reg) {
      const float v = gacc[mt][reg] + bgv;
      float m = (r < 7) ? v : -3.0e38f;
      #pragma unroll
      for (int mk = 1; mk < 16; mk <<= 1) m = fmaxf(m, __shfl_xor(m, mk, 16));
      const float e = (r < 7) ? __expf(v - m) : 0.f;
      float s = e;
      #pragma unroll
      for (int mk = 1; mk < 16; mk <<= 1) s += __shfl_xor(s, mk, 16);
      const int b = mt * 16 + q * 4 + reg;
      if (r < 7) wbuf[b * WSTR + i * 8 + r] = (e / s) * gbuf[b * WSTR + i * 8 + r];
    }
  }
  // no barrier: wbuf cols of node i produced/consumed by wave i only; zh untouched

  // ---------------- dense: h = (z_i + sum_k w_k z_nk) @ W_i + b ----------------
  v4f acc[2][NT];
  #pragma unroll
  for (int mt = 0; mt < 2; ++mt)
    #pragma unroll
    for (int n = 0; n < NT; ++n) acc[mt][n] = (v4f){0.f,0.f,0.f,0.f};

  _Float16 wh[2][7];
  #pragma unroll
  for (int mt = 0; mt < 2; ++mt)
    #pragma unroll
    for (int nb = 0; nb < 7; ++nb)
      wh[mt][nb] = (_Float16)wbuf[(mt * 16 + r) * WSTR + i * 8 + nb];

  #pragma unroll
  for (int ks = 0; ks < KS; ++ks) {
    const int d0 = ks * 32 + q * 8;
    v8h dbn[NT];
    if (ks + 1 < KS) {
      #pragma unroll
      for (int n = 0; n < NT; ++n)
        dbn[n] = *(const v8h*)(WB + (size_t)n * 16 * D + (ks + 1) * 32);  // prefetch
    }
    v8h x01[2];
    #pragma unroll
    for (int mt = 0; mt < 2; ++mt) {
      v8h zn[7];
      #pragma unroll
      for (int nb = 0; nb < 7; ++nb) {
        const int nk = nb + (nb >= i);
        zn[nb] = *(const v8h*)(zh + ((nk * NB + mt * 16 + r) * DSTR + d0));
      }
      v8h x = *(const v8h*)(zh + ((i * NB + mt * 16 + r) * DSTR + d0));
      x = (x + (zn[0] * wh[mt][0] + zn[1] * wh[mt][1]))
        + ((zn[2] * wh[mt][2] + zn[3] * wh[mt][3])
        + ((zn[4] * wh[mt][4] + zn[5] * wh[mt][5]) + zn[6] * wh[mt][6]));
      x01[mt] = x;
    }
    #pragma unroll
    for (int n = 0; n < NT; ++n) {
      acc[0][n] = __builtin_amdgcn_mfma_f32_16x16x32_f16(x01[0], dbf[n], acc[0][n], 0, 0, 0);
      acc[1][n] = __builtin_amdgcn_mfma_f32_16x16x32_f16(x01[1], dbf[n], acc[1][n], 0, 0, 0);
    }
    if (ks + 1 < KS) {
      #pragma unroll
      for (int n = 0; n < NT; ++n) dbf[n] = dbn[n];
    }
  }

  // cross-phase prefetch: issue next phase's B-frags now; LN + 2 barriers cover them
  #pragma unroll
  for (int t = 0; t < NPRE; ++t)
    pre[t] = *(const v8h*)(preBase + (size_t)t * preStride);

  // bias + LayerNorm + relu in regs (C/D: col=n*16+r, row=mt*16+q*4+reg)
  float bv[NT], gv[NT], bev[NT];
  #pragma unroll
  for (int n = 0; n < NT; ++n) {
    const int o = n * 16 + r;
    bv[n] = bias[i * O + o]; gv[n] = g[i * O + o]; bev[n] = be[i * O + o];
  }
  #pragma unroll
  for (int mt = 0; mt < 2; ++mt) {
    #pragma unroll
    for (int reg = 0; reg < 4; ++reg) {
      float s1 = 0.f, s2 = 0.f;
      #pragma unroll
      for (int n = 0; n < NT; ++n) {
        const float h = acc[mt][n][reg] + bv[n];
        acc[mt][n][reg] = h;
        s1 += h; s2 += h * h;
      }
      #pragma unroll
      for (int mk = 1; mk < 16; mk <<= 1) { s1 += __shfl_xor(s1, mk, 16); s2 += __shfl_xor(s2, mk, 16); }
      const float mean = s1 * (1.f / O);
      const float var  = s2 * (1.f / O) - mean * mean;
      const float rs   = rsqrtf(var + EPSLN);
      #pragma unroll
      for (int n = 0; n < NT; ++n) {
        const float h = (acc[mt][n][reg] - mean) * rs * gv[n] + bev[n];
        acc[mt][n][reg] = fmaxf(h, 0.f);
      }
    }
  }
  __syncthreads();   // all waves done reading zh before overwrite
  #pragma unroll
  for (int mt = 0; mt < 2; ++mt)
    #pragma unroll
    for (int n = 0; n < NT; ++n)
      #pragma unroll
      for (int reg = 0; reg < 4; ++reg) {
        const int b = mt * 16 + q * 4 + reg;
        zh[(i * NB + b) * DSTR + n * 16 + r] = (_Float16)acc[mt][n][reg];
      }
  __syncthreads();
}

__launch_bounds__(512, 2)
__global__ void actor_mfma(KP p)
{
  __shared__ __align__(16) _Float16 zh[8 * NB * DSTR];   // [node][b][d]  135.2 KB
  __shared__ float wbuf[NB * WSTR];                      // 8.7 KB
  __shared__ float gbuf[NB * WSTR];                      // 8.7 KB
  __shared__ float xbuf[8 * NB * 4];                     // 4.0 KB

  const int i = threadIdx.x >> 6;        // wave = node
  const int u = threadIdx.x & 63;
  const int q = u >> 4, r = u & 15;
  const int bbase = blockIdx.x * NB;

  // ---- init: Z (f16) + gates
  {
    #pragma unroll
    for (int c = 0; c < 2; ++c) {
      const int idx = c * 64 + u;
      if (idx < NB * 3) {
        const int b = idx / 3, d = idx - 3 * (idx / 3);
        zh[(i * NB + b) * DSTR + d] = (_Float16)p.Z[i][(size_t)(bbase + b) * 3 + d];
      }
    }
    for (int t = threadIdx.x; t < NB * 64; t += 512) {
      const int b = t >> 6, ik = t & 63;
      const int ii = ik >> 3, k = ik & 7;
      if (k < 7) {
        const int j = k + (k >= ii);
        const int gidx = (ii == 0 && j <= 3) ? j : 8 * j + ii;
        gbuf[b * WSTR + ik] = p.A[(size_t)(bbase + b) * 64 + gidx];
      }
    }
  }
  __syncthreads();

  // ================= layer 0 (VALU, tiny K) =================
  for (int c = 0; c < NB / 8; ++c) {
    const int b = c * 8 + (u >> 3), o8 = u & 7;
    float v = -3.0e38f;
    if (o8 < 7) {
      v = p.bg0[i * 7 + o8];
      #pragma unroll
      for (int k = 0; k < 7; ++k) {
        const int nk = k + (k >= i);
        const _Float16* zp = zh + (nk * NB + b) * DSTR;
        const float* wp = p.Wg0 + (i * 21 + k * 3) * 7 + o8;
        v += (float)zp[0] * wp[0] + (float)zp[1] * wp[7] + (float)zp[2] * wp[14];
      }
    }
    float m = v;
    #pragma unroll
    for (int mk = 1; mk < 8; mk <<= 1) m = fmaxf(m, __shfl_xor(m, mk, 8));
    const float e = (o8 < 7) ? __expf(v - m) : 0.f;
    float s = e;
    #pragma unroll
    for (int mk = 1; mk < 8; mk <<= 1) s += __shfl_xor(s, mk, 8);
    if (o8 < 7) wbuf[b * WSTR + i * 8 + o8] = (e / s) * gbuf[b * WSTR + i * 8 + o8];
  }
  // wbuf cols same-wave -> no barrier
  // NZ0 -> xbuf (same-wave rows; zh read-only since init barrier)
  #pragma unroll
  for (int c = 0; c < 2; ++c) {
    const int idx = c * 64 + u;
    if (idx < NB * 3) {
      const int b = idx / 3, d = idx - 3 * (idx / 3);
      float x = (float)zh[(i * NB + b) * DSTR + d];
      #pragma unroll
      for (int k = 0; k < 7; ++k) {
        const int nk = k + (k >= i);
        x += wbuf[b * WSTR + i * 8 + k] * (float)zh[(nk * NB + b) * DSTR + d];
      }
      xbuf[(i * NB + b) * 4 + d] = x;
    }
  }
  // prefetch layer-1 gate B-frags: fly during the barrier + dense0
  v8h gpre1[7];
  {
    const _Float16* gb = p.WgT1 + (size_t)(i * 8 + r) * (7 * 256) + q * 8;
    #pragma unroll
    for (int nb = 0; nb < 7; ++nb) gpre1[nb] = *(const v8h*)(gb + nb * 256);
  }
  // REQUIRED barrier: dense0 overwrites zh[i][b][*] while other waves may still
  // read zh[nk=i][b][d<3] above (cross-wave WAR). (R7's bug was removing this.)
  __syncthreads();
  // dense0: O=256, K=3 ; writes zh[i][b][0..255]
  {
    const int bh = u >> 5, lo = u & 31, o = lo * 8;
    float w0r[3][8], b0r[8], g0r[8], be0r[8];
    #pragma unroll
    for (int d = 0; d < 3; ++d)
      #pragma unroll
      for (int j = 0; j < 8; ++j) w0r[d][j] = p.W0[(i * 3 + d) * 256 + o + j];
    #pragma unroll
    for (int j = 0; j < 8; ++j) {
      b0r[j] = p.b0[i * 256 + o + j];
      g0r[j] = p.g0[i * 256 + o + j];
      be0r[j] = p.be0[i * 256 + o + j];
    }
    for (int it = 0; it < NB / 2; ++it) {
      const int b = it * 2 + bh;
      const float x0 = xbuf[(i * NB + b) * 4 + 0];
      const float x1 = xbuf[(i * NB + b) * 4 + 1];
      const float x2 = xbuf[(i * NB + b) * 4 + 2];
      float h[8], s1 = 0.f, s2 = 0.f;
      #pragma unroll
      for (int j = 0; j < 8; ++j) {
        const float v = b0r[j] + x0 * w0r[0][j] + x1 * w0r[1][j] + x2 * w0r[2][j];
        h[j] = v; s1 += v; s2 += v * v;
      }
      #pragma unroll
      for (int mk = 1; mk < 32; mk <<= 1) { s1 += __shfl_xor(s1, mk, 32); s2 += __shfl_xor(s2, mk, 32); }
      const float mean = s1 * (1.f / 256.f);
      const float var  = s2 * (1.f / 256.f) - mean * mean;
      const float rs   = rsqrtf(var + EPSLN);
      v8h hv;
      #pragma unroll
      for (int j = 0; j < 8; ++j)
        hv[j] = (_Float16)fmaxf((h[j] - mean) * rs * g0r[j] + be0r[j], 0.f);
      *(v8h*)(zh + (i * NB + b) * DSTR + o) = hv;
    }
  }
  __syncthreads();

  // ================= layers 1,2 (MFMA) with cross-phase prefetch =================
  v8h gpre2[7], wpre[8];
  mfma_layer<256, 128, 7>(zh, wbuf, gbuf, gpre1, p.WgT1, p.bg1, p.WT1, p.b1, p.g1, p.be1,
                          p.WgT2 + (size_t)(i * 8 + r) * (7 * 128) + q * 8, 128, gpre2, i, q, r);
  mfma_layer<128, 64, 8>(zh, wbuf, gbuf, gpre2, p.WgT2, p.bg2, p.WT2, p.b2, p.g2, p.be2,
                         p.WoT + (size_t)(i * 8 + (u & 7)) * 64, 8, wpre, i, q, r);

  // ================= output 64 -> 5, tanh (VALU; weights preloaded in wpre) =====
  {
    const int b8 = u >> 3, o8 = u & 7;
    const float bo = (o8 < 5) ? p.bout[i * 5 + o8] : 0.f;
    for (int c = 0; c < NB / 8; ++c) {
      const int b = c * 8 + b8;
      const _Float16* zp = zh + (i * NB + b) * DSTR;
      float acc = bo;
      #pragma unroll
      for (int t8 = 0; t8 < 8; ++t8) {
        const v8h z8 = *(const v8h*)(zp + t8 * 8);
        #pragma unroll
        for (int j = 0; j < 8; ++j) acc += (float)z8[j] * (float)wpre[t8][j];
      }
      if (o8 < 5)
        p.out[((size_t)(bbase + b) * 8 + i) * 5 + o8] = tanhf(acc);
    }
  }
}

extern "C" void kernel_launch(void* const* d_in, const int* in_sizes, int n_in,
                              void* d_out, int out_size, void* d_ws, size_t ws_size,
                              hipStream_t stream) {
  KP p;
  for (int i = 0; i < 8; ++i) p.Z[i] = (const float*)d_in[1 + i];
  p.A   = (const float*)d_in[9];
  p.W0  = (const float*)d_in[10]; p.b0 = (const float*)d_in[11];
  p.g0  = (const float*)d_in[12]; p.be0 = (const float*)d_in[13];
  p.Wg0 = (const float*)d_in[14]; p.bg0 = (const float*)d_in[15];
  const float* W1  = (const float*)d_in[16]; p.b1 = (const float*)d_in[17];
  p.g1  = (const float*)d_in[18]; p.be1 = (const float*)d_in[19];
  const float* Wg1 = (const float*)d_in[20]; p.bg1 = (const float*)d_in[21];
  const float* W2  = (const float*)d_in[22]; p.b2 = (const float*)d_in[23];
  p.g2  = (const float*)d_in[24]; p.be2 = (const float*)d_in[25];
  const float* Wg2 = (const float*)d_in[26]; p.bg2 = (const float*)d_in[27];
  const float* Wout = (const float*)d_in[28]; p.bout = (const float*)d_in[29];
  p.out = (float*)d_out;

  _Float16* wsH = (_Float16*)d_ws;
  p.WgT1 = wsH;
  p.WgT2 = wsH + E1;
  p.WoT  = wsH + E1 + E2;
  p.WT1  = wsH + E1 + E2 + E3;
  p.WT2  = wsH + E1 + E2 + E3 + E4;

  const int total = E1 + E2 + E3 + E4 + E5;  // 503808
  hipLaunchKernelGGL(cvt_all, dim3((total + 255) / 256), dim3(256), 0, stream,
                     Wg1, Wg2, Wout, W1, W2, wsH);

  hipLaunchKernelGGL(actor_mfma, dim3(8192 / NB), dim3(512), 0, stream, p);
}